// Round 1
// baseline (65.556 us; speedup 1.0000x reference)
//
#include <hip/hip_runtime.h>
#include <cmath>

#define NCLUST   64
#define TSTEPS   32
#define BATCH    64
#define DIM      4096
#define NTHREADS 1024
#define NPT      (DIM / NTHREADS)   // 4 neurons per thread, strided by 1024
#define NWAVES   (NTHREADS / 64)    // 16

// One block per batch row b. Thread tid owns neurons d = tid + j*1024,
// all of which live in cluster (tid & 63) since 1024 % 64 == 0.
// State carried in double so we track the f64 numpy reference exactly
// (spike threshold crossings are discrete -> must not flip).
__global__ __launch_bounds__(NTHREADS)
void alif_fwd(const float* __restrict__ x_in,      // (T,B,D)
              const float* __restrict__ threshold, // (D)
              const float* __restrict__ bm_raw,    // scalar
              const float* __restrict__ bs_raw,    // scalar
              const float* __restrict__ nw,        // (NC,NC)
              const float* __restrict__ gain,      // (NC)
              float* __restrict__ out_s,           // (T,B,D)
              float* __restrict__ out_v)           // (T,B,D)
{
    // sWT[c*64 + c'] = sigmoid(nw[c'][c])  (transposed so matvec reads are
    // consecutive-per-lane -> bank-conflict-free)
    __shared__ double sWT[NCLUST * NCLUST];
    __shared__ double sGain[NCLUST];
    __shared__ double sPart[NWAVES * NCLUST];
    __shared__ double sCf[NCLUST];
    __shared__ double sCasc[NCLUST];

    const int tid  = threadIdx.x;
    const int lane = tid & 63;
    const int wav  = tid >> 6;
    const int b    = blockIdx.x;

    // One-time per block: sigmoid(neighbor_weights), stored transposed.
    for (int i = tid; i < NCLUST * NCLUST; i += NTHREADS) {
        double w   = (double)nw[i];
        double sig = 1.0 / (1.0 + exp(-w));
        int cp = i >> 6, c = i & 63;          // nw is [c'][c] row-major
        sWT[c * NCLUST + cp] = sig;
    }
    if (tid < NCLUST) sGain[tid] = (double)gain[tid];

    const double beta_m = 1.0 / (1.0 + exp(-(double)bm_raw[0]));
    const double beta_s = 1.0 / (1.0 + exp(-(double)bs_raw[0]));
    const double ombm   = 1.0 - beta_m;
    const double vreset = (double)(-0.1f);    // reference materializes V_RESET as f32

    double v[NPT], isyn[NPT], th[NPT];
    int refrac[NPT];
#pragma unroll
    for (int j = 0; j < NPT; j++) {
        v[j] = 0.0; isyn[j] = 0.0; refrac[j] = 0;
        th[j] = (double)threshold[tid + j * NTHREADS];
    }

    const size_t strideT = (size_t)BATCH * DIM;
    const float* xb = x_in + (size_t)b * DIM;
    float* sb = out_s + (size_t)b * DIM;
    float* vb = out_v + (size_t)b * DIM;

    // Software prefetch: xf holds x_t, xn is loaded for t+1 during step t.
    float xf[NPT];
#pragma unroll
    for (int j = 0; j < NPT; j++) xf[j] = xb[tid + j * NTHREADS];

    __syncthreads();

    for (int t = 0; t < TSTEPS; t++) {
        float xn[NPT];
        if (t + 1 < TSTEPS) {
            const float* xt1 = xb + (size_t)(t + 1) * strideT;
#pragma unroll
            for (int j = 0; j < NPT; j++) xn[j] = xt1[tid + j * NTHREADS];
        } else {
#pragma unroll
            for (int j = 0; j < NPT; j++) xn[j] = 0.0f;
        }

        // --- state update + spike ---
        float s[NPT];
        double part = 0.0;
#pragma unroll
        for (int j = 0; j < NPT; j++) {
            isyn[j] = beta_s * isyn[j] + (double)xf[j];
            double vn = beta_m * v[j] + ombm * isyn[j];
            double vv = (refrac[j] > 0) ? vreset : vn;
            v[j] = vv;
            bool sp = (vv >= th[j]);
            s[j] = sp ? 1.0f : 0.0f;
            part += sp ? 1.0 : 0.0;
        }

        // --- per-cluster counts: wave-partial -> 16-wave reduce ---
        sPart[wav * NCLUST + lane] = part;
        __syncthreads();

        if (tid < NCLUST) {
            double cf = 0.0;
#pragma unroll
            for (int w = 0; w < NWAVES; w++) cf += sPart[w * NCLUST + tid];
            sCf[tid] = cf * (1.0 / 64.0);     // counts/64 is exact
        }
        __syncthreads();

        // --- 64x64 matvec: cascade[c'] = gain[c'] * sum_c cf[c]*Wsig[c'][c] ---
        if (tid < NCLUST) {
            double acc = 0.0;
#pragma unroll
            for (int c = 0; c < NCLUST; c++)
                acc += sCf[c] * sWT[c * NCLUST + tid];  // broadcast + consecutive
            sCasc[tid] = acc * sGain[tid];
        }
        __syncthreads();

        // --- apply cascade, reset, refractory, write outputs ---
        const double casc = sCasc[lane];
        float* st = sb + (size_t)t * strideT;
        float* vt = vb + (size_t)t * strideT;
#pragma unroll
        for (int j = 0; j < NPT; j++) {
            isyn[j] += casc;
            v[j] -= (double)s[j] * th[j];
            refrac[j] = (s[j] > 0.0f) ? 2 : (refrac[j] > 0 ? refrac[j] - 1 : 0);
            st[tid + j * NTHREADS] = s[j];
            vt[tid + j * NTHREADS] = (float)v[j];
        }
#pragma unroll
        for (int j = 0; j < NPT; j++) xf[j] = xn[j];
    }
}

extern "C" void kernel_launch(void* const* d_in, const int* in_sizes, int n_in,
                              void* d_out, int out_size, void* d_ws, size_t ws_size,
                              hipStream_t stream) {
    const float* x  = (const float*)d_in[0];
    const float* th = (const float*)d_in[1];
    const float* bm = (const float*)d_in[2];
    const float* bs = (const float*)d_in[3];
    const float* nw = (const float*)d_in[4];
    const float* gn = (const float*)d_in[5];
    float* out_s = (float*)d_out;
    float* out_v = out_s + (size_t)TSTEPS * BATCH * DIM;

    hipLaunchKernelGGL(alif_fwd, dim3(BATCH), dim3(NTHREADS), 0, stream,
                       x, th, bm, bs, nw, gn, out_s, out_v);
}